// Round 7
// baseline (56.513 us; speedup 1.0000x reference)
//
#include <hip/hip_runtime.h>
#include <hip/hip_cooperative_groups.h>
#include <math.h>

namespace cg = cooperative_groups;

#define BB 2
#define NN 512
#define NIN 64
#define NF 192
#define HH 128
#define NOUT 8

typedef short short8 __attribute__((ext_vector_type(8)));
typedef float f32x4 __attribute__((ext_vector_type(4)));

__device__ __forceinline__ float celu1(float x) {
    return x > 0.0f ? x : expm1f(x);
}

__device__ __forceinline__ ushort f2b(float f) {
    union { float f; uint u; } v; v.f = f;
    uint r = v.u + 0x7fffu + ((v.u >> 16) & 1u);   // RNE
    return (ushort)(r >> 16);
}
__device__ __forceinline__ uint pack2(float a, float b) {
    return (uint)f2b(a) | ((uint)f2b(b) << 16);
}
// load 8 consecutive f32, convert to a bf16 MFMA fragment in-register
__device__ __forceinline__ short8 cvt8(const float* __restrict__ p) {
    float4 a = *(const float4*)p;
    float4 b = *(const float4*)(p + 4);
    union { uint4 u; short8 s; } c;
    c.u.x = pack2(a.x, a.y); c.u.y = pack2(a.z, a.w);
    c.u.z = pack2(b.x, b.y); c.u.w = pack2(b.z, b.w);
    return c.s;
}

// t_s XOR swizzle (validated in R6): byte = m*256 + (col*2 ^ (key(m)<<4)),
// key(m) = (m ^ (m>>3)) & 7.  Phase-1 ds_write_b64 (dm=8/lane) and phase-2
// ds_read_b128 (dm=1/lane) both land 2-way max (free).
__device__ __forceinline__ ushort* tsw(ushort* t_s, int m, int col) {
    int key = (m ^ (m >> 3)) & 7;
    int byte = m * 256 + ((col * 2) ^ (key << 4));
    return (ushort*)((char*)t_s + byte);
}

// ---------------------------------------------------------------------------
// Single cooperative kernel, grid 256 x 512 threads (1 block/CU, 8 waves).
// Stage A: waves 0-3: fc layer via MFMA (pairing folded into B-frag address,
//          in-register f32->bf16 cvt; blk role = bid, same math as old k1).
//          waves 4-7: Wb transpose unit bid: o = bid>>5, 4 g-rows.
// grid.sync()
// Stage B: fused t + out (R6 body). Phase 1: wave w computes o=w slice of the
//          t-tile into swizzled LDS. Phase 2: wave = (j-pair, ms-half); each
//          LDS A-read feeds 2 MFMAs (j-subtiles) -> 128 KB ds_read/block.
// ---------------------------------------------------------------------------
__global__ __launch_bounds__(512) void fused_kernel(
    const float* __restrict__ x_l, const float* __restrict__ x_r,
    const float* __restrict__ Wl, const float* __restrict__ bl,
    const float* __restrict__ Wr, const float* __restrict__ br,
    const float* __restrict__ Wb, const float* __restrict__ bias_b,
    ushort* __restrict__ hl_bf, ushort* __restrict__ hr_bf,
    ushort* __restrict__ Wt, float* __restrict__ out)
{
    __shared__ ushort t_s[128 * 128];   // 32 KiB, stage B only

    int bid = blockIdx.x;
    int tid = threadIdx.x;
    int lane = tid & 63;
    int lrow = lane & 15;
    int lgrp = lane >> 4;

    // ================= stage A =================
    if (tid < 256) {
        // ---- fc: blk role = bid ----
        int mb = bid & 63;
        int lr = (bid >> 6) & 1;
        int hh = bid >> 7;
        int m0 = mb * 16;
        int b  = m0 >> 9;
        int i_base = m0 & (NN - 1);
        int wave4 = tid >> 6;            // 0..3
        int h0 = hh * 64 + wave4 * 16;
        int i = i_base + lrow;

        const float* Wm   = lr ? Wr : Wl;
        const float* bias = lr ? br : bl;
        const float* xa   = lr ? x_r : x_l;
        ushort* dst       = lr ? hr_bf : hl_bf;

        short8 bf[6];
        #pragma unroll
        for (int kk = 0; kk < 6; ++kk) {
            int part = kk >> 1;
            int c0 = (kk & 1) * 32 + lgrp * 8;
            int s; const float* src;
            if (part == 0)      { s = 0;            src = x_l; }
            else if (part == 1) { s = lr ? +1 : -1; src = xa; }
            else                { s = lr ? -1 : +1; src = xa; }
            int row = i + s;
            short8 v = (short8)0;
            if ((unsigned)row < (unsigned)NN)
                v = cvt8(&src[(b * NN + row) * NIN + c0]);
            bf[kk] = v;
        }

        f32x4 acc = (f32x4)(0.0f);
        #pragma unroll
        for (int kk = 0; kk < 6; ++kk) {
            short8 afrag = cvt8(&Wm[(h0 + lrow) * NF + kk * 32 + lgrp * 8]);
            acc = __builtin_amdgcn_mfma_f32_16x16x32_bf16(afrag, bf[kk], acc, 0, 0, 0);
        }

        int h_base = h0 + lgrp * 4;
        float4 bv = *(const float4*)&bias[h_base];
        int m = m0 + lrow;
        uint2 v;
        v.x = pack2(celu1(acc[0] + bv.x), celu1(acc[1] + bv.y));
        v.y = pack2(celu1(acc[2] + bv.z), celu1(acc[3] + bv.w));
        *(uint2*)&dst[m * HH + h_base] = v;
    } else {
        // ---- Wb transpose: unit bid -> o, 4 g-rows of Wt[o] ----
        int t2 = tid - 256;
        int o  = bid >> 5;
        int g4 = (bid & 31) * 4;
        int h  = t2 & 127;
        int gs = t2 >> 7;                // 0/1
        #pragma unroll
        for (int q = 0; q < 2; ++q) {
            int gg = g4 + gs + q * 2;
            Wt[(o * HH + gg) * HH + h] = f2b(Wb[(o * HH + h) * HH + gg]);
        }
    }

    cg::this_grid().sync();

    // ================= stage B =================
    int j0 = (bid & 3) * 128;
    int i0 = ((bid >> 2) & 31) * 16;
    int b  = bid >> 7;
    int wave = tid >> 6;                 // 0..7

    // ---- prefetch phase-2 B fragments: wave = (j-pair, ms-half) ----
    int jp = wave & 3;                   // j-pair index
    int mh = wave >> 2;                  // ms-half: ms in [mh*4, mh*4+4)
    const ushort* hb = hr_bf + (size_t)b * NN * HH;
    short8 bfr[2][4];
    #pragma unroll
    for (int js = 0; js < 2; ++js) {
        int jw = j0 + (jp * 2 + js) * 16;
        #pragma unroll
        for (int kk = 0; kk < 4; ++kk)
            bfr[js][kk] = *(const short8*)&hb[(jw + lrow) * HH + kk * 32 + lgrp * 8];
    }

    // ---- phase 1: build t tile in swizzled LDS (wave w -> o = w) ----
    short8 hfrag[4];
    #pragma unroll
    for (int kk = 0; kk < 4; ++kk)
        hfrag[kk] = *(const short8*)&hl_bf[(b * NN + i0 + lrow) * HH + kk * 32 + lgrp * 8];

    int o_p1 = wave;
    #pragma unroll
    for (int gt = 0; gt < 8; ++gt) {
        int g_base = gt * 16;
        f32x4 acc = (f32x4)(0.0f);
        #pragma unroll
        for (int kk = 0; kk < 4; ++kk) {
            short8 afrag = *(const short8*)&Wt[(o_p1 * HH + g_base + lrow) * HH + kk * 32 + lgrp * 8];
            acc = __builtin_amdgcn_mfma_f32_16x16x32_bf16(afrag, hfrag[kk], acc, 0, 0, 0);
        }
        // lane: i = lrow (D col), g = g_base + lgrp*4 + r (D row)
        int m  = lrow * 8 + o_p1;
        int gg = g_base + lgrp * 4;
        uint2 v;
        v.x = pack2(acc[0], acc[1]);
        v.y = pack2(acc[2], acc[3]);
        *(uint2*)tsw(t_s, m, gg) = v;
    }
    __syncthreads();

    // ---- phase 2: A from LDS, each read feeds 2 MFMAs ----
    f32x4 acc2[4][2];
    #pragma unroll
    for (int s = 0; s < 4; ++s)
        #pragma unroll
        for (int js = 0; js < 2; ++js) acc2[s][js] = (f32x4)(0.0f);

    #pragma unroll
    for (int kk = 0; kk < 4; ++kk) {
        int koff = kk * 32 + lgrp * 8;
        #pragma unroll
        for (int s = 0; s < 4; ++s) {
            int ms = mh * 4 + s;
            short8 afr = *(const short8*)tsw(t_s, ms * 16 + lrow, koff);
            #pragma unroll
            for (int js = 0; js < 2; ++js)
                acc2[s][js] = __builtin_amdgcn_mfma_f32_16x16x32_bf16(afr, bfr[js][kk], acc2[s][js], 0, 0, 0);
        }
    }

    // ---- epilogue: D rows = m (4 consecutive -> same i, o0..o0+3), cols = j ----
    float4 b0 = *(const float4*)&bias_b[0];
    float4 b1 = *(const float4*)&bias_b[4];

    #pragma unroll
    for (int s = 0; s < 4; ++s) {
        int m_base = (mh * 4 + s) * 16 + lgrp * 4;   // multiple of 4
        int i  = i0 + (m_base >> 3);
        int o0 = m_base & 7;                          // 0 or 4
        float4 bv = o0 ? b1 : b0;
        #pragma unroll
        for (int js = 0; js < 2; ++js) {
            int j = j0 + (jp * 2 + js) * 16 + lrow;
            float4 v;
            v.x = acc2[s][js][0] + bv.x;
            v.y = acc2[s][js][1] + bv.y;
            v.z = acc2[s][js][2] + bv.z;
            v.w = acc2[s][js][3] + bv.w;
            float* dst = out + ((size_t)((b * NN + i) * NN + j)) * NOUT + o0;
            *(float4*)dst = v;
        }
    }
}

// ---------------------------------------------------------------------------
extern "C" void kernel_launch(void* const* d_in, const int* in_sizes, int n_in,
                              void* d_out, int out_size, void* d_ws, size_t ws_size,
                              hipStream_t stream) {
    const float* x_l  = (const float*)d_in[0];
    const float* x_r  = (const float*)d_in[1];
    const float* Wl   = (const float*)d_in[2];
    const float* bl   = (const float*)d_in[3];
    const float* Wr   = (const float*)d_in[4];
    const float* br   = (const float*)d_in[5];
    const float* Wb   = (const float*)d_in[6];
    const float* bb   = (const float*)d_in[7];
    float* out = (float*)d_out;

    ushort* hl_bf = (ushort*)d_ws;                   // B*N*H = 131072
    ushort* hr_bf = hl_bf + BB * NN * HH;            // 131072
    ushort* Wt    = hr_bf + BB * NN * HH;            // 8*128*128 = 131072

    void* args[] = { (void*)&x_l, (void*)&x_r, (void*)&Wl, (void*)&bl,
                     (void*)&Wr, (void*)&br, (void*)&Wb, (void*)&bb,
                     (void*)&hl_bf, (void*)&hr_bf, (void*)&Wt, (void*)&out };
    hipLaunchCooperativeKernel((const void*)fused_kernel, dim3(256), dim3(512),
                               args, 0, stream);
}

// Round 8
// 29.603 us; speedup vs baseline: 1.9090x; 1.9090x over previous
//
#include <hip/hip_runtime.h>
#include <math.h>

#define BB 2
#define NN 512
#define NIN 64
#define NF 192
#define HH 128
#define NOUT 8

typedef short short8 __attribute__((ext_vector_type(8)));
typedef float f32x4 __attribute__((ext_vector_type(4)));

__device__ __forceinline__ float celu1(float x) {
    return x > 0.0f ? x : expm1f(x);
}

__device__ __forceinline__ ushort f2b(float f) {
    union { float f; uint u; } v; v.f = f;
    uint r = v.u + 0x7fffu + ((v.u >> 16) & 1u);   // RNE
    return (ushort)(r >> 16);
}
__device__ __forceinline__ uint pack2(float a, float b) {
    return (uint)f2b(a) | ((uint)f2b(b) << 16);
}
// load 8 consecutive f32, convert to a bf16 MFMA fragment in-register
__device__ __forceinline__ short8 cvt8(const float* __restrict__ p) {
    float4 a = *(const float4*)p;
    float4 b = *(const float4*)(p + 4);
    union { uint4 u; short8 s; } c;
    c.u.x = pack2(a.x, a.y); c.u.y = pack2(a.z, a.w);
    c.u.z = pack2(b.x, b.y); c.u.w = pack2(b.z, b.w);
    return c.s;
}

// ---------------------------------------------------------------------------
// K1: blocks [0,256): fc layer via MFMA, reading f32 x/W with in-register cvt.
//     blk = mb | (lr<<6) | (hh<<7).  Pairing folded into B-frag addressing.
//     blocks [256,264): transpose+cvt bilinear_W[o][h][g] -> Wt[o][g][h].
// (validated R4/R6)
// ---------------------------------------------------------------------------
__global__ __launch_bounds__(256) void k1_kernel(
    const float* __restrict__ x_l, const float* __restrict__ x_r,
    const float* __restrict__ Wl, const float* __restrict__ bl,
    const float* __restrict__ Wr, const float* __restrict__ br,
    const float* __restrict__ Wb,
    ushort* __restrict__ hl_bf, ushort* __restrict__ hr_bf,
    ushort* __restrict__ Wt)
{
    __shared__ float lds[128 * 65];   // used only by transpose blocks
    int blk = blockIdx.x;
    int tid = threadIdx.x;

    if (blk < 256) {
        int mb = blk & 63;
        int lr = (blk >> 6) & 1;
        int hh = blk >> 7;
        int m0 = mb * 16;
        int b  = m0 >> 9;
        int i_base = m0 & (NN - 1);

        int wave = tid >> 6;
        int lane = tid & 63;
        int lrow = lane & 15;
        int lgrp = lane >> 4;
        int h0 = hh * 64 + wave * 16;
        int i = i_base + lrow;

        const float* Wm   = lr ? Wr : Wl;
        const float* bias = lr ? br : bl;
        const float* xa   = lr ? x_r : x_l;
        ushort* dst       = lr ? hr_bf : hl_bf;

        // B-fragments: pairing folded into address
        short8 bf[6];
        #pragma unroll
        for (int kk = 0; kk < 6; ++kk) {
            int part = kk >> 1;
            int c0 = (kk & 1) * 32 + lgrp * 8;
            int s; const float* src;
            if (part == 0)      { s = 0;            src = x_l; }
            else if (part == 1) { s = lr ? +1 : -1; src = xa; }
            else                { s = lr ? -1 : +1; src = xa; }
            int row = i + s;
            short8 v = (short8)0;
            if ((unsigned)row < (unsigned)NN)
                v = cvt8(&src[(b * NN + row) * NIN + c0]);
            bf[kk] = v;
        }

        f32x4 acc = (f32x4)(0.0f);
        #pragma unroll
        for (int kk = 0; kk < 6; ++kk) {
            short8 afrag = cvt8(&Wm[(h0 + lrow) * NF + kk * 32 + lgrp * 8]);
            acc = __builtin_amdgcn_mfma_f32_16x16x32_bf16(afrag, bf[kk], acc, 0, 0, 0);
        }

        int h_base = h0 + lgrp * 4;
        float4 bv = *(const float4*)&bias[h_base];
        int m = m0 + lrow;
        uint2 v;
        v.x = pack2(celu1(acc[0] + bv.x), celu1(acc[1] + bv.y));
        v.y = pack2(celu1(acc[2] + bv.z), celu1(acc[3] + bv.w));
        *(uint2*)&dst[m * HH + h_base] = v;
    } else {
        int o = blk - 256;
        for (int h0 = 0; h0 < HH; h0 += 64) {
            for (int idx = tid; idx < 64 * 128; idx += 256) {
                int hh = idx >> 7;           // 0..63
                int g  = idx & 127;
                lds[g * 65 + hh] = Wb[(o * HH + h0 + hh) * HH + g];
            }
            __syncthreads();
            for (int idx = tid; idx < 128 * 64; idx += 256) {
                int g  = idx >> 6;           // 0..127
                int hh = idx & 63;
                Wt[(o * HH + g) * HH + h0 + hh] = f2b(lds[g * 65 + hh]);
            }
            __syncthreads();
        }
    }
}

// ---------------------------------------------------------------------------
// kT: t[m][o][g] = sum_h hl[m][h] * W[o][h][g], via MFMA with
// D[g][m] = Wt[o] (A, rows=g) x hl^T (B, cols=m).  All frags contiguous 16B.
// grid: dim3(16, 8) = (m-block of 64, o), 256 threads (4 waves, 16 m each).
// (validated R2)
// ---------------------------------------------------------------------------
__global__ __launch_bounds__(256) void t_kernel(
    const ushort* __restrict__ hl_bf, const ushort* __restrict__ Wt,
    ushort* __restrict__ t_bf)
{
    int o  = blockIdx.y;
    int m0 = blockIdx.x * 64;
    int tid  = threadIdx.x;
    int wave = tid >> 6;
    int lane = tid & 63;
    int lrow = lane & 15;
    int lgrp = lane >> 4;

    int m_wave = m0 + wave * 16;

    f32x4 acc[8];
    #pragma unroll
    for (int gt = 0; gt < 8; ++gt) acc[gt] = (f32x4)(0.0f);

    const ushort* Wo = Wt + o * HH * HH;

    #pragma unroll
    for (int kk = 0; kk < 4; ++kk) {
        int koff = kk * 32 + lgrp * 8;
        short8 a[8];
        #pragma unroll
        for (int gt = 0; gt < 8; ++gt)
            a[gt] = *(const short8*)&Wo[(gt * 16 + lrow) * HH + koff];
        short8 bfrag = *(const short8*)&hl_bf[(m_wave + lrow) * HH + koff];
        #pragma unroll
        for (int gt = 0; gt < 8; ++gt)
            acc[gt] = __builtin_amdgcn_mfma_f32_16x16x32_bf16(a[gt], bfrag, acc[gt], 0, 0, 0);
    }

    int m = m_wave + lrow;
    #pragma unroll
    for (int gt = 0; gt < 8; ++gt) {
        int g0 = gt * 16 + lgrp * 4;
        uint lo = (uint)f2b(acc[gt][0]) | ((uint)f2b(acc[gt][1]) << 16);
        uint hi = (uint)f2b(acc[gt][2]) | ((uint)f2b(acc[gt][3]) << 16);
        uint2 v; v.x = lo; v.y = hi;
        *(uint2*)&t_bf[(m * NOUT + o) * HH + g0] = v;
    }
}

// ---------------------------------------------------------------------------
// K2: out[b,i,j,o] = sum_g t[b,(i,o)][g] * hr[b,j][g] + bias[o]
// GEMM per batch: M=4096 (=(i,o)), N=512 (=j), K=128.  MFMA 16x16x32.
// grid: dim3(N/128, M/64, B) = 512 blocks (2/CU), 256 threads (4 waves;
// wave = 32 j, 64 m).  All fragments 16B contiguous from global; no LDS.
// (validated R2)
// ---------------------------------------------------------------------------
__global__ __launch_bounds__(256) void out_kernel(
    const ushort* __restrict__ t_bf, const ushort* __restrict__ hr_bf,
    const float* __restrict__ bias, float* __restrict__ out)
{
    int b  = blockIdx.z;
    int m0 = blockIdx.y * 64;
    int j0 = blockIdx.x * 128;
    int tid  = threadIdx.x;
    int wave = tid >> 6;
    int lane = tid & 63;
    int lrow = lane & 15;
    int lgrp = lane >> 4;

    int jw = j0 + wave * 32;

    f32x4 acc[4][2];
    #pragma unroll
    for (int mt = 0; mt < 4; ++mt)
        #pragma unroll
        for (int jt = 0; jt < 2; ++jt) acc[mt][jt] = (f32x4)(0.0f);

    const ushort* tb = t_bf + (size_t)b * (NN * NOUT) * HH;
    const ushort* hb = hr_bf + (size_t)b * NN * HH;

    #pragma unroll
    for (int kk = 0; kk < 4; ++kk) {
        int koff = kk * 32 + lgrp * 8;
        short8 a[4], bf[2];
        #pragma unroll
        for (int mt = 0; mt < 4; ++mt)
            a[mt] = *(const short8*)&tb[(m0 + mt * 16 + lrow) * HH + koff];
        #pragma unroll
        for (int jt = 0; jt < 2; ++jt)
            bf[jt] = *(const short8*)&hb[(jw + jt * 16 + lrow) * HH + koff];
        #pragma unroll
        for (int mt = 0; mt < 4; ++mt)
            #pragma unroll
            for (int jt = 0; jt < 2; ++jt)
                acc[mt][jt] = __builtin_amdgcn_mfma_f32_16x16x32_bf16(a[mt], bf[jt], acc[mt][jt], 0, 0, 0);
    }

    float4 b0 = *(const float4*)&bias[0];
    float4 b1 = *(const float4*)&bias[4];

    #pragma unroll
    for (int mt = 0; mt < 4; ++mt) {
        int m_base = m0 + mt * 16 + lgrp * 4;   // multiple of 4
        int i  = m_base >> 3;
        int o0 = m_base & 7;                    // 0 or 4
        float4 bv = o0 ? b1 : b0;
        #pragma unroll
        for (int jt = 0; jt < 2; ++jt) {
            int j = jw + jt * 16 + lrow;
            float4 v;
            v.x = acc[mt][jt][0] + bv.x;
            v.y = acc[mt][jt][1] + bv.y;
            v.z = acc[mt][jt][2] + bv.z;
            v.w = acc[mt][jt][3] + bv.w;
            float* dst = out + ((size_t)((b * NN + i) * NN + j)) * NOUT + o0;
            *(float4*)dst = v;
        }
    }
}

// ---------------------------------------------------------------------------
extern "C" void kernel_launch(void* const* d_in, const int* in_sizes, int n_in,
                              void* d_out, int out_size, void* d_ws, size_t ws_size,
                              hipStream_t stream) {
    const float* x_l  = (const float*)d_in[0];
    const float* x_r  = (const float*)d_in[1];
    const float* Wl   = (const float*)d_in[2];
    const float* bl   = (const float*)d_in[3];
    const float* Wr   = (const float*)d_in[4];
    const float* br   = (const float*)d_in[5];
    const float* Wb   = (const float*)d_in[6];
    const float* bb   = (const float*)d_in[7];
    float* out = (float*)d_out;

    ushort* hl_bf = (ushort*)d_ws;                   // B*N*H = 131072
    ushort* hr_bf = hl_bf + BB * NN * HH;            // 131072
    ushort* Wt    = hr_bf + BB * NN * HH;            // 8*128*128 = 131072
    ushort* t_bf  = Wt + NOUT * HH * HH;             // B*N*8*H = 1048576

    k1_kernel<<<264, 256, 0, stream>>>(x_l, x_r, Wl, bl, Wr, br, Wb,
                                       hl_bf, hr_bf, Wt);
    t_kernel<<<dim3(16, NOUT), 256, 0, stream>>>(hl_bf, Wt, t_bf);
    out_kernel<<<dim3(NN / 128, 4096 / 64, BB), 256, 0, stream>>>(
        t_bf, hr_bf, bb, out);
}